// Round 13
// baseline (100.037 us; speedup 1.0000x reference)
//
#include <hip/hip_runtime.h>

// out[co*4+n, ci*4+o, y, x] = sum_{c,ky,kx} k1[co*4+n, ci*4+c, y+ky-7, x+kx-7]
//                                         * k2[co*4+o, ci*4+c, ky, kx]
// MFMA per (co,ci,c,ky):  OUT[y][x] (o=0..3) += sum_u Apad[y+ky][u] * k2[o][ky][u-x]
//   A-frag: lane(y=l&15, kg=l>>4) reads 8 contiguous bf16 (ds_read_b128)
//   B-frag (R13): DIRECT dword reads from 2-phase SoA weight tables.
//     W[c][o] = contiguous zero-padded row per ky (stride 34 elems, data at 15..29).
//     Two copies: P0[e]=W[e], P1[e]=W[e+1]. Lane needs words (W[b+2t],W[b+2t+1]),
//     b = 8*kg - x + 15: ph = b&1 picks the copy, m = (b-ph)/2 -> the 4 frag words
//     are 4 CONSECUTIVE dwords at m+17*ky (imm offsets, DS-merge -> ds_read2_b32).
//     ZERO v_perm / repack VALU in the K-loop (R9 spent 16 perms/iter).
// R12 lesson: epilogue slab y-stride must keep f32x4 16B-aligned (stride 17 dwords
//   made 3/4 of lanes' b128 writes misaligned -> +17us). R9 stride-20 epilogue kept.
// R11/R12 attribution: setprio was neutral; misaligned epilogue was the regression.
// 8 waves (512 thr), wave = (c = wid&3, np = wid>>2 handling n in {2np,2np+1}).
// Apad 2-D shared-pad tiling: 8 vertical bands (stride 22 rows) x 2 horizontal
//   (cols 0/24); only the discarded yl=15 output row ever reads neighbor data.
// Zero-share: row stride 34; max touched elem 46 < 34+15 (next row's first data).

typedef float f32x4 __attribute__((ext_vector_type(4)));
typedef __bf16 bf16x8 __attribute__((ext_vector_type(8)));
typedef unsigned u32x4v __attribute__((ext_vector_type(4)));

#define KS 15
#define SP 225
#define NCH 256
#define RSTRIDE 56                    // shorts per Apad row
#define ROWS 183                      // 22*7 + 29
#define APAD_SHORTS (ROWS * RSTRIDE)  // 10248 shorts = 20496 B
#define TBL_OFF (APAD_SHORTS * 2)     // 20496 B, 16B aligned
#define WROW 34                       // elems per ky row (even -> dword rows)
#define WSZ  524                      // elems per (c,o,ph): 14*34+47, rounded even
#define ARENA_B (TBL_OFF + 32 * WSZ * 2)   // 20496 + 33536 = 54032 B

__device__ __forceinline__ unsigned short f2bf(float f) {
    unsigned u = __builtin_bit_cast(unsigned, f);
    u += 0x7FFFu + ((u >> 16) & 1u);   // RNE (finite normals)
    return (unsigned short)(u >> 16);
}

__global__ __launch_bounds__(512, 6)
void blade_conv_mfma(const float* __restrict__ k1,
                     const float* __restrict__ k2,
                     float* __restrict__ out) {
    // phase 1: Apad bf16 [183 rows][56 cols] + Wt tables [4c][4o][2ph][524 elems]
    // phase 2: slabs f32 [8 wid][2 oi][16 x][20 y] = 20480 B (overlays Apad only)
    __shared__ __align__(16) unsigned char arena[ARENA_B];
    unsigned short* Apad  = (unsigned short*)arena;
    unsigned short* Wt    = (unsigned short*)(arena + TBL_OFF);
    float*          slabs = (float*)arena;

    const int tid  = threadIdx.x;
    const int lane = tid & 63;
    const int wid  = tid >> 6;            // 8 waves
    const int c_w  = wid & 3;             // input channel c
    const int np   = wid >> 2;            // n-half: n in {2np, 2np+1}
    const int co = blockIdx.x, ci = blockIdx.y;

    // ---- zero whole arena (54032/16 = 3377 f32x4) ----
    f32x4 z = {0.f, 0.f, 0.f, 0.f};
    for (int i = tid; i < ARENA_B / 16; i += 512) ((f32x4*)arena)[i] = z;
    __syncthreads();

    // ---- staging: thread (lo < 225, half) owns one (y,x) cell ----
    {
        const int lo = tid & 255, half = tid >> 8;
        if (lo < 225) {
            const int y = lo / 15, x = lo - y * 15;
            // k1: planes 8*half .. 8*half+7  (n = 2*half + j>>2, c = j&3)
            #pragma unroll
            for (int j = 0; j < 8; ++j) {
                int n = 2 * half + (j >> 2), cc = j & 3;
                float v = k1[((size_t)((co * 4 + n) * NCH + ci * 4 + cc)) * SP + lo];
                int band = n * 2 + (cc >> 1), side = cc & 1;
                Apad[(band * 22 + 7 + y) * RSTRIDE + side * 24 + 7 + x] = f2bf(v);
            }
            // k2: channels cc = 2*half, 2*half+1; write both phase copies
            #pragma unroll
            for (int jj = 0; jj < 2; ++jj) {
                int cc = 2 * half + jj;
                size_t base = ((size_t)(co * 4) * NCH + ci * 4 + cc) * SP + lo;  // o=0
                #pragma unroll
                for (int o = 0; o < 4; ++o) {
                    float v = k2[base + (size_t)o * NCH * SP];
                    unsigned short h = f2bf(v);
                    int tb = ((cc * 4 + o) * 2) * WSZ + WROW * y;
                    Wt[tb + 15 + x]       = h;   // ph0: P0[e] = W[e]
                    Wt[tb + WSZ + 14 + x] = h;   // ph1: P1[e] = W[e+1]
                }
            }
        }
    }
    __syncthreads();

    // ---- K loop: 15 ky chunks, K=32 (u) each ----
    f32x4 acc[2][4];
    #pragma unroll
    for (int g = 0; g < 2; ++g)
        #pragma unroll
        for (int o = 0; o < 4; ++o)
            acc[g][o] = z;

    const int yl    = lane & 15;       // output y (M); also consuming x for B
    const int kg    = lane >> 4;       // k-group
    const int side_w = c_w & 1, whalf = c_w >> 1;
    const int acol  = side_w * 24 + (kg << 3);
    const int b     = (kg << 3) - yl + 15;   // in [0, 39]
    const int ph    = b & 1;
    const int m     = (b - ph) >> 1;         // dword base within a row
    const unsigned* tdw = (const unsigned*)Wt;
    const unsigned* tb0 = tdw + ((c_w * 4 + 0) * 2 + ph) * (WSZ / 2) + m;
    const unsigned* tb1 = tdw + ((c_w * 4 + 1) * 2 + ph) * (WSZ / 2) + m;
    const unsigned* tb2 = tdw + ((c_w * 4 + 2) * 2 + ph) * (WSZ / 2) + m;
    const unsigned* tb3 = tdw + ((c_w * 4 + 3) * 2 + ph) * (WSZ / 2) + m;
    const unsigned short* ab0 =
        &Apad[(((2 * np + 0) * 2 + whalf) * 22 + yl) * RSTRIDE + acol];
    const unsigned short* ab1 =
        &Apad[(((2 * np + 1) * 2 + whalf) * 22 + yl) * RSTRIDE + acol];

    #pragma unroll
    for (int ky = 0; ky < 15; ++ky) {
        bf16x8 af0 = *(const bf16x8*)(ab0 + ky * RSTRIDE);
        bf16x8 af1 = *(const bf16x8*)(ab1 + ky * RSTRIDE);

        u32x4v w0, w1, w2, w3;
        #pragma unroll
        for (int t = 0; t < 4; ++t) {
            w0[t] = tb0[17 * ky + t];   // 17 dwords = WROW/2 row stride
            w1[t] = tb1[17 * ky + t];
            w2[t] = tb2[17 * ky + t];
            w3[t] = tb3[17 * ky + t];
        }
        bf16x8 b0v = __builtin_bit_cast(bf16x8, w0);
        bf16x8 b1v = __builtin_bit_cast(bf16x8, w1);
        bf16x8 b2v = __builtin_bit_cast(bf16x8, w2);
        bf16x8 b3v = __builtin_bit_cast(bf16x8, w3);

        acc[0][0] = __builtin_amdgcn_mfma_f32_16x16x32_bf16(af0, b0v, acc[0][0], 0, 0, 0);
        acc[0][1] = __builtin_amdgcn_mfma_f32_16x16x32_bf16(af0, b1v, acc[0][1], 0, 0, 0);
        acc[0][2] = __builtin_amdgcn_mfma_f32_16x16x32_bf16(af0, b2v, acc[0][2], 0, 0, 0);
        acc[0][3] = __builtin_amdgcn_mfma_f32_16x16x32_bf16(af0, b3v, acc[0][3], 0, 0, 0);
        acc[1][0] = __builtin_amdgcn_mfma_f32_16x16x32_bf16(af1, b0v, acc[1][0], 0, 0, 0);
        acc[1][1] = __builtin_amdgcn_mfma_f32_16x16x32_bf16(af1, b1v, acc[1][1], 0, 0, 0);
        acc[1][2] = __builtin_amdgcn_mfma_f32_16x16x32_bf16(af1, b2v, acc[1][2], 0, 0, 0);
        acc[1][3] = __builtin_amdgcn_mfma_f32_16x16x32_bf16(af1, b3v, acc[1][3], 0, 0, 0);
    }

    // ---- cross-wave (c) reduction: 4 rounds (g = r>>1, o-pair = r&1) ----
    // R9-proven epilogue: slab [8 wid][2 oi][16 x][20 y] (stride 20 -> aligned b128)
    const int xl = lane & 15;
    #pragma unroll
    for (int r = 0; r < 4; ++r) {
        const int g = r >> 1, op = r & 1;
        __syncthreads();   // r=0: Apad/tbl reads done; r>0: prev readout done
        {
            float* slab = slabs + wid * 640;   // [2 oi][16 x][20 y]
            #pragma unroll
            for (int oi = 0; oi < 2; ++oi)
                *(f32x4*)&slab[(oi * 16 + xl) * 20 + (kg << 2)] = acc[g][2 * op + oi];
        }
        __syncthreads();
        for (int idx = tid; idx < 900; idx += 512) {
            int q4 = idx / 225;                 // 0..3 = (np_g, oi)
            int rem = idx - q4 * 225;
            int np_g = q4 >> 1, oi = q4 & 1;
            int yy = rem / 15, xx = rem - yy * 15;
            int soff = (oi * 16 + xx) * 20 + yy;
            const float* sb = slabs + np_g * 2560;
            float s = sb[soff] + sb[640 + soff] + sb[1280 + soff] + sb[1920 + soff];
            int n = 2 * np_g + g, o = 2 * op + oi;
            out[((size_t)((co * 4 + n) * NCH + ci * 4 + o)) * SP + rem] = s;
        }
    }
}

extern "C" void kernel_launch(void* const* d_in, const int* in_sizes, int n_in,
                              void* d_out, int out_size, void* d_ws, size_t ws_size,
                              hipStream_t stream) {
    (void)in_sizes; (void)n_in; (void)d_ws; (void)ws_size; (void)out_size;
    const float* k1 = (const float*)d_in[0];
    const float* k2 = (const float*)d_in[1];
    float* out = (float*)d_out;

    dim3 grid(64, 64, 1);
    dim3 block(512, 1, 1);
    hipLaunchKernelGGL(blade_conv_mfma, grid, block, 0, stream, k1, k2, out);
}

// Round 14
// 75.679 us; speedup vs baseline: 1.3218x; 1.3218x over previous
//
#include <hip/hip_runtime.h>

// out[co*4+n, ci*4+o, y, x] = sum_{c,ky,kx} k1[co*4+n, ci*4+c, y+ky-7, x+kx-7]
//                                         * k2[co*4+o, ci*4+c, ky, kx]
// MFMA per (co,ci,c,ky):  OUT[y][x] (o=0..3) += sum_u Apad[y+ky][u] * k2[o][ky][u-x]
//   A-frag: lane(y=l&15, kg=l>>4) reads 8 contiguous bf16 (ds_read_b128)
//   B-frag: 8x ds_read_b64 from o-interleaved zero-padded Toeplitz table + v_perm.
// R14 = R9 verbatim (85.6us champion) + vectorized epilogue READOUT only.
// Hard-won structure laws (R10/R11/R12/R13):
//   - B-path MUST be contiguous 8B/lane b64 reads + v_perm repack. Direct
//     fragment reads (b32 streams) lose 20% twice (R10, R13: conflicts 3.5x).
//   - Epilogue slab f32x4 stores need y-stride mult of 4 dwords (R12: stride 17
//     misaligned 3/4 of b128 writes, +17us). Stride 20: 2-way conflicts only.
//   - setprio in this symmetric-wave loop: neutral (R11/R12 attribution).
// 8 waves (512 thr), wave = (c = wid&3, np = wid>>2 handling n in {2np,2np+1}).
// Apad 2-D shared-pad tiling: 8 vertical bands (stride 22 rows) x 2 horizontal
//   (cols 0/24); only the discarded yl=15 output row ever reads neighbor data.
// Toeplitz tbl rows stride 32 units share zeros (window 46 < next row's data 47).

typedef float f32x4 __attribute__((ext_vector_type(4)));
typedef __bf16 bf16x8 __attribute__((ext_vector_type(8)));

#define KS 15
#define SP 225
#define NCH 256
#define RSTRIDE 56                    // shorts per Apad row
#define ROWS 183                      // 22*7 + 29
#define APAD_SHORTS (ROWS * RSTRIDE)  // 10248 shorts = 20496 B
#define TBL_OFF (APAD_SHORTS * 2)     // 20496 B, 16B aligned
#define TBL_UPC 496                   // table units (8B) per input channel c
#define ARENA_B (TBL_OFF + 4 * TBL_UPC * 8)   // 36368 B

__device__ __forceinline__ unsigned short f2bf(float f) {
    unsigned u = __builtin_bit_cast(unsigned, f);
    u += 0x7FFFu + ((u >> 16) & 1u);   // RNE (finite normals)
    return (unsigned short)(u >> 16);
}

__global__ __launch_bounds__(512, 6)
void blade_conv_mfma(const float* __restrict__ k1,
                     const float* __restrict__ k2,
                     float* __restrict__ out) {
    // phase 1: Apad bf16 [183 rows][56 cols] + Toeplitz tbl [4c][496 u64]
    // phase 2: slabs f32 [8 wid][2 oi][16 x][20 y] = 20480 B (overlays Apad only)
    __shared__ __align__(16) unsigned char arena[ARENA_B];
    unsigned short*     Apad  = (unsigned short*)arena;
    unsigned long long* tbl   = (unsigned long long*)(arena + TBL_OFF);
    float*              slabs = (float*)arena;

    const int tid  = threadIdx.x;
    const int lane = tid & 63;
    const int wid  = tid >> 6;            // 8 waves
    const int c_w  = wid & 3;             // input channel c
    const int np   = wid >> 2;            // n-half: n in {2np, 2np+1}
    const int co = blockIdx.x, ci = blockIdx.y;

    // ---- zero whole arena (36368/16 = 2273 f32x4) ----
    f32x4 z = {0.f, 0.f, 0.f, 0.f};
    for (int i = tid; i < ARENA_B / 16; i += 512) ((f32x4*)arena)[i] = z;
    __syncthreads();

    // ---- staging: thread (lo < 225, half) owns one (y,x) cell ----
    {
        const int lo = tid & 255, half = tid >> 8;
        if (lo < 225) {
            const int y = lo / 15, x = lo - y * 15;
            // k1: planes 8*half .. 8*half+7  (n = 2*half + j>>2, c = j&3)
            #pragma unroll
            for (int j = 0; j < 8; ++j) {
                int n = 2 * half + (j >> 2), cc = j & 3;
                float v = k1[((size_t)((co * 4 + n) * NCH + ci * 4 + cc)) * SP + lo];
                int band = n * 2 + (cc >> 1), side = cc & 1;
                Apad[(band * 22 + 7 + y) * RSTRIDE + side * 24 + 7 + x] = f2bf(v);
            }
            // k2: channels c = 2*half, 2*half+1  (ky=y, kx=x)
            #pragma unroll
            for (int jj = 0; jj < 2; ++jj) {
                int cc = 2 * half + jj;
                size_t base = ((size_t)(co * 4) * NCH + ci * 4 + cc) * SP + lo;  // o=0
                float v0 = k2[base];
                float v1 = k2[base + (size_t)NCH * SP];
                float v2 = k2[base + 2 * (size_t)NCH * SP];
                float v3 = k2[base + 3 * (size_t)NCH * SP];
                unsigned lw = (unsigned)f2bf(v0) | ((unsigned)f2bf(v1) << 16);
                unsigned hw = (unsigned)f2bf(v2) | ((unsigned)f2bf(v3) << 16);
                tbl[cc * TBL_UPC + 32 * y + x + 15] =
                    (unsigned long long)lw | ((unsigned long long)hw << 32);
            }
        }
    }
    __syncthreads();

    // ---- K loop: 15 ky chunks, K=32 (u) each ----
    f32x4 acc[2][4];
    #pragma unroll
    for (int g = 0; g < 2; ++g)
        #pragma unroll
        for (int o = 0; o < 4; ++o)
            acc[g][o] = z;

    const int yl    = lane & 15;       // output y (M); also consuming x for B
    const int kg    = lane >> 4;       // k-group
    const int side_w = c_w & 1, whalf = c_w >> 1;
    const int acol  = side_w * 24 + (kg << 3);
    const unsigned long long* tbase =
        &tbl[c_w * TBL_UPC + (kg << 3) - yl + 15];

    #pragma unroll
    for (int ky = 0; ky < 15; ++ky) {
        bf16x8 af[2];
        #pragma unroll
        for (int g = 0; g < 2; ++g) {
            int band = (2 * np + g) * 2 + whalf;
            af[g] = *(const bf16x8*)&Apad[(band * 22 + yl + ky) * RSTRIDE + acol];
        }
        unsigned long long q[8];
        #pragma unroll
        for (int j = 0; j < 8; ++j) q[j] = tbase[32 * ky + j];

        union { bf16x8 v; unsigned u[4]; } bo0, bo1, bo2, bo3;
        #pragma unroll
        for (int t = 0; t < 4; ++t) {
            unsigned a0 = (unsigned)q[2 * t],         a1 = (unsigned)q[2 * t + 1];
            unsigned b0 = (unsigned)(q[2 * t] >> 32), b1 = (unsigned)(q[2 * t + 1] >> 32);
            bo0.u[t] = __builtin_amdgcn_perm(a1, a0, 0x05040100u);
            bo1.u[t] = __builtin_amdgcn_perm(a1, a0, 0x07060302u);
            bo2.u[t] = __builtin_amdgcn_perm(b1, b0, 0x05040100u);
            bo3.u[t] = __builtin_amdgcn_perm(b1, b0, 0x07060302u);
        }
        #pragma unroll
        for (int g = 0; g < 2; ++g) {
            acc[g][0] = __builtin_amdgcn_mfma_f32_16x16x32_bf16(af[g], bo0.v, acc[g][0], 0, 0, 0);
            acc[g][1] = __builtin_amdgcn_mfma_f32_16x16x32_bf16(af[g], bo1.v, acc[g][1], 0, 0, 0);
            acc[g][2] = __builtin_amdgcn_mfma_f32_16x16x32_bf16(af[g], bo2.v, acc[g][2], 0, 0, 0);
            acc[g][3] = __builtin_amdgcn_mfma_f32_16x16x32_bf16(af[g], bo3.v, acc[g][3], 0, 0, 0);
        }
    }

    // ---- cross-wave (c) reduction: 4 rounds (g = r>>1, o-pair = r&1) ----
    // writes identical to R9; readout vectorized: thread = (q4, xx, y-quad),
    // 4x aligned f32x4 slab reads + vector sum + <=4 scalar global stores.
    const int xl = lane & 15;
    #pragma unroll
    for (int r = 0; r < 4; ++r) {
        const int g = r >> 1, op = r & 1;
        __syncthreads();   // r=0: Apad/tbl reads done; r>0: prev readout done
        {
            float* slab = slabs + wid * 640;   // [2 oi][16 x][20 y]
            #pragma unroll
            for (int oi = 0; oi < 2; ++oi)
                *(f32x4*)&slab[(oi * 16 + xl) * 20 + (kg << 2)] = acc[g][2 * op + oi];
        }
        __syncthreads();
        if (tid < 240) {
            const int q4 = tid / 60;            // (np_g, oi)
            const int s  = tid - q4 * 60;
            const int xx = s >> 2, yq = s & 3;  // y-quad: rows 4yq..4yq+3
            const int np_g = q4 >> 1, oi = q4 & 1;
            const int soff = (oi * 16 + xx) * 20 + (yq << 2);
            const float* sb = slabs + np_g * 2560;
            f32x4 v0 = *(const f32x4*)&sb[soff];
            f32x4 v1 = *(const f32x4*)&sb[640 + soff];
            f32x4 v2 = *(const f32x4*)&sb[1280 + soff];
            f32x4 v3 = *(const f32x4*)&sb[1920 + soff];
            f32x4 sum = v0 + v1 + v2 + v3;
            const int n = 2 * np_g + g, o = 2 * op + oi;
            float* po = out + ((size_t)((co * 4 + n) * NCH + ci * 4 + o)) * SP
                      + (yq << 2) * 15 + xx;
            #pragma unroll
            for (int i = 0; i < 4; ++i)
                if ((yq << 2) + i < 15) po[i * 15] = sum[i];
        }
    }
}

extern "C" void kernel_launch(void* const* d_in, const int* in_sizes, int n_in,
                              void* d_out, int out_size, void* d_ws, size_t ws_size,
                              hipStream_t stream) {
    (void)in_sizes; (void)n_in; (void)d_ws; (void)ws_size; (void)out_size;
    const float* k1 = (const float*)d_in[0];
    const float* k2 = (const float*)d_in[1];
    float* out = (float*)d_out;

    dim3 grid(64, 64, 1);
    dim3 block(512, 1, 1);
    hipLaunchKernelGGL(blade_conv_mfma, grid, block, 0, stream, k1, k2, out);
}